// Round 1
// baseline (1966.714 us; speedup 1.0000x reference)
//
#include <hip/hip_runtime.h>
#include <math.h>

// Problem constants (B=2, S=2048, D=1024, H=16, DEPTH=64)
#define B_ 2
#define S_ 2048
#define D_ 1024
#define H_ 16
#define DH_ 64

// GEMM tiling: 64x64 block tile, K-tile 16, 256 threads (16x16), 4x4 per thread
#define BM 64
#define BN 64
#define BK 16

// ---------------------------------------------------------------------------
// Shared NT-GEMM core: acc[4][4] += A[64 x K] * W[64 x K]^T  (both row-major,
// contiguous along K — the torch nn.Linear "x @ W.T" layout).
// A, W are pre-offset to the tile origin. lda/ldw are row strides in elems.
// ---------------------------------------------------------------------------
__device__ __forceinline__ void gemm_nt_tile(const float* __restrict__ A, int lda,
                                             const float* __restrict__ W, int ldw,
                                             int K, float acc[4][4]) {
  __shared__ float As[BM][BK + 1];  // +1 pad breaks bank conflicts
  __shared__ float Bs[BN][BK + 1];
  const int tx = threadIdx.x, ty = threadIdx.y;
  const int tid = ty * 16 + tx;
  const int lrow = tid >> 2;          // 0..63
  const int lc4 = (tid & 3) << 2;     // 0,4,8,12

#pragma unroll
  for (int i = 0; i < 4; ++i)
#pragma unroll
    for (int j = 0; j < 4; ++j) acc[i][j] = 0.f;

  for (int k0 = 0; k0 < K; k0 += BK) {
    // issue global loads before the barrier so they overlap the prior MACs
    const float4 av = *(const float4*)(A + (size_t)lrow * lda + k0 + lc4);
    const float4 bv = *(const float4*)(W + (size_t)lrow * ldw + k0 + lc4);
    __syncthreads();
    As[lrow][lc4 + 0] = av.x; As[lrow][lc4 + 1] = av.y;
    As[lrow][lc4 + 2] = av.z; As[lrow][lc4 + 3] = av.w;
    Bs[lrow][lc4 + 0] = bv.x; Bs[lrow][lc4 + 1] = bv.y;
    Bs[lrow][lc4 + 2] = bv.z; Bs[lrow][lc4 + 3] = bv.w;
    __syncthreads();
#pragma unroll
    for (int kk = 0; kk < BK; ++kk) {
      float a[4], b[4];
#pragma unroll
      for (int i = 0; i < 4; ++i) a[i] = As[ty * 4 + i][kk];
#pragma unroll
      for (int j = 0; j < 4; ++j) b[j] = Bs[tx * 4 + j][kk];
#pragma unroll
      for (int i = 0; i < 4; ++i)
#pragma unroll
        for (int j = 0; j < 4; ++j) acc[i][j] += a[i] * b[j];
    }
  }
}

// ---------------------------------------------------------------------------
// QKV projection: y = x @ W.T + b, scattered to head-split [B,H,S,DH]
// ---------------------------------------------------------------------------
__global__ __launch_bounds__(256) void qkv_proj_kernel(
    const float* __restrict__ x, const float* __restrict__ W,
    const float* __restrict__ bias, float* __restrict__ outh) {
  const int n0 = blockIdx.x * BN, m0 = blockIdx.y * BM;
  float acc[4][4];
  gemm_nt_tile(x + (size_t)m0 * D_, D_, W + (size_t)n0 * D_, D_, D_, acc);
  const int tx = threadIdx.x, ty = threadIdx.y;
#pragma unroll
  for (int i = 0; i < 4; ++i) {
    const int m = m0 + ty * 4 + i;
    const int b = m >> 11;            // m / S_
    const int s = m & (S_ - 1);
#pragma unroll
    for (int j = 0; j < 4; ++j) {
      const int n = n0 + tx * 4 + j;
      const int h = n >> 6;           // n / DH_
      const int dd = n & (DH_ - 1);
      outh[((size_t)(b * H_ + h) * S_ + s) * DH_ + dd] = acc[i][j] + bias[n];
    }
  }
}

// ---------------------------------------------------------------------------
// Scores: logits = (qh @ kh^T) / 8 + mask * -1e9, per (b,h), into attn region
// ---------------------------------------------------------------------------
__global__ __launch_bounds__(256) void scores_kernel(
    const float* __restrict__ qh, const float* __restrict__ kh,
    const float* __restrict__ mask, float* __restrict__ attn) {
  const int z = blockIdx.z;                 // b*H + h
  const int n0 = blockIdx.x * BN, m0 = blockIdx.y * BM;
  const float* A = qh + (size_t)z * S_ * DH_ + (size_t)m0 * DH_;
  const float* W = kh + (size_t)z * S_ * DH_ + (size_t)n0 * DH_;
  float acc[4][4];
  gemm_nt_tile(A, DH_, W, DH_, DH_, acc);
  const int b = z >> 4;                     // z / H_
  float* out = attn + (size_t)z * S_ * S_;
  const int tx = threadIdx.x, ty = threadIdx.y;
#pragma unroll
  for (int i = 0; i < 4; ++i) {
    const int q = m0 + ty * 4 + i;
#pragma unroll
    for (int j = 0; j < 4; ++j) {
      const int k = n0 + tx * 4 + j;
      out[(size_t)q * S_ + k] = acc[i][j] * 0.125f + mask[b * S_ + k] * (-1e9f);
    }
  }
}

// ---------------------------------------------------------------------------
// In-place row softmax over attn rows of length S_ (one block per row)
// ---------------------------------------------------------------------------
__global__ __launch_bounds__(256) void softmax_kernel(float* __restrict__ attn) {
  __shared__ float red[8];
  const int row = blockIdx.x;
  float* p = attn + (size_t)row * S_;
  const int tid = threadIdx.x;
  float v[8];
  float mx = -3.4e38f;
#pragma unroll
  for (int i = 0; i < 8; ++i) {
    v[i] = p[tid + 256 * i];
    mx = fmaxf(mx, v[i]);
  }
#pragma unroll
  for (int off = 32; off > 0; off >>= 1) mx = fmaxf(mx, __shfl_down(mx, off, 64));
  if ((tid & 63) == 0) red[tid >> 6] = mx;
  __syncthreads();
  mx = fmaxf(fmaxf(red[0], red[1]), fmaxf(red[2], red[3]));
  float s = 0.f;
#pragma unroll
  for (int i = 0; i < 8; ++i) {
    v[i] = __expf(v[i] - mx);
    s += v[i];
  }
#pragma unroll
  for (int off = 32; off > 0; off >>= 1) s += __shfl_down(s, off, 64);
  if ((tid & 63) == 0) red[4 + (tid >> 6)] = s;
  __syncthreads();
  s = red[4] + red[5] + red[6] + red[7];
  const float inv = 1.f / s;
#pragma unroll
  for (int i = 0; i < 8; ++i) p[tid + 256 * i] = v[i] * inv;
}

// ---------------------------------------------------------------------------
// PV: ctx[b,s,h*64+dd] = sum_k attn[b,h,s,k] * vh[b,h,k,dd]   (NN GEMM)
// ---------------------------------------------------------------------------
__global__ __launch_bounds__(256) void pv_kernel(
    const float* __restrict__ attn, const float* __restrict__ vh,
    float* __restrict__ ctx) {
  __shared__ float As[BM][BK + 1];
  __shared__ float Bs[BK][BN + 4];   // +4 keeps float4 alignment & spreads banks
  const int z = blockIdx.z;
  const int m0 = blockIdx.y * BM;    // n0 == 0 (BN == DH_... full depth in one tile? no: BN=64=DH_, yes)
  const int tx = threadIdx.x, ty = threadIdx.y;
  const int tid = ty * 16 + tx;
  const int arow = tid >> 2, ac4 = (tid & 3) << 2;
  const int brow = tid >> 4, bc4 = (tid & 15) << 2;
  const float* A = attn + (size_t)z * S_ * S_ + (size_t)m0 * S_;
  const float* Bv = vh + (size_t)z * S_ * DH_;
  float acc[4][4];
#pragma unroll
  for (int i = 0; i < 4; ++i)
#pragma unroll
    for (int j = 0; j < 4; ++j) acc[i][j] = 0.f;

  for (int k0 = 0; k0 < S_; k0 += BK) {
    const float4 av = *(const float4*)(A + (size_t)arow * S_ + k0 + ac4);
    const float4 bv = *(const float4*)(Bv + (size_t)(k0 + brow) * DH_ + bc4);
    __syncthreads();
    As[arow][ac4 + 0] = av.x; As[arow][ac4 + 1] = av.y;
    As[arow][ac4 + 2] = av.z; As[arow][ac4 + 3] = av.w;
    Bs[brow][bc4 + 0] = bv.x; Bs[brow][bc4 + 1] = bv.y;
    Bs[brow][bc4 + 2] = bv.z; Bs[brow][bc4 + 3] = bv.w;
    __syncthreads();
#pragma unroll
    for (int kk = 0; kk < BK; ++kk) {
      float a[4], b[4];
#pragma unroll
      for (int i = 0; i < 4; ++i) a[i] = As[ty * 4 + i][kk];
#pragma unroll
      for (int j = 0; j < 4; ++j) b[j] = Bs[kk][tx * 4 + j];
#pragma unroll
      for (int i = 0; i < 4; ++i)
#pragma unroll
        for (int j = 0; j < 4; ++j) acc[i][j] += a[i] * b[j];
    }
  }
  const int b = z >> 4, h = z & (H_ - 1);
#pragma unroll
  for (int i = 0; i < 4; ++i) {
    const int m = m0 + ty * 4 + i;  // q index within batch
#pragma unroll
    for (int j = 0; j < 4; ++j) {
      const int dd = tx * 4 + j;
      ctx[(size_t)(b * S_ + m) * D_ + h * DH_ + dd] = acc[i][j];
    }
  }
}

// ---------------------------------------------------------------------------
// Output projection: out = ctx @ wo.T + bo, flat [B*S, D]
// ---------------------------------------------------------------------------
__global__ __launch_bounds__(256) void out_proj_kernel(
    const float* __restrict__ ctx, const float* __restrict__ W,
    const float* __restrict__ bias, float* __restrict__ out) {
  const int n0 = blockIdx.x * BN, m0 = blockIdx.y * BM;
  float acc[4][4];
  gemm_nt_tile(ctx + (size_t)m0 * D_, D_, W + (size_t)n0 * D_, D_, D_, acc);
  const int tx = threadIdx.x, ty = threadIdx.y;
#pragma unroll
  for (int i = 0; i < 4; ++i) {
    const int m = m0 + ty * 4 + i;
#pragma unroll
    for (int j = 0; j < 4; ++j) {
      const int n = n0 + tx * 4 + j;
      out[(size_t)m * D_ + n] = acc[i][j] + bias[n];
    }
  }
}

// ---------------------------------------------------------------------------
extern "C" void kernel_launch(void* const* d_in, const int* in_sizes, int n_in,
                              void* d_out, int out_size, void* d_ws, size_t ws_size,
                              hipStream_t stream) {
  const float* q    = (const float*)d_in[0];
  const float* k    = (const float*)d_in[1];
  const float* v    = (const float*)d_in[2];
  const float* mask = (const float*)d_in[3];
  const float* wq   = (const float*)d_in[4];
  const float* bq   = (const float*)d_in[5];
  const float* wk   = (const float*)d_in[6];
  const float* bk   = (const float*)d_in[7];
  const float* wv   = (const float*)d_in[8];
  const float* bv   = (const float*)d_in[9];
  const float* wo   = (const float*)d_in[10];
  const float* bo   = (const float*)d_in[11];

  float* out  = (float*)d_out;                          // [B,S,D]
  float* attn = out + (size_t)B_ * S_ * D_;             // [B,H,S,S]

  // workspace: qh, kh, vh (head-split [B,H,S,DH]) + ctx (flat [B,S,D]) = 64 MB
  float* qh  = (float*)d_ws;
  float* kh  = qh + (size_t)B_ * S_ * D_;
  float* vh  = kh + (size_t)B_ * S_ * D_;
  float* ctx = vh + (size_t)B_ * S_ * D_;

  dim3 blk(16, 16);
  dim3 gproj(D_ / BN, (B_ * S_) / BM);                  // (16, 64)
  qkv_proj_kernel<<<gproj, blk, 0, stream>>>(q, wq, bq, qh);
  qkv_proj_kernel<<<gproj, blk, 0, stream>>>(k, wk, bk, kh);
  qkv_proj_kernel<<<gproj, blk, 0, stream>>>(v, wv, bv, vh);

  dim3 gsc(S_ / BN, S_ / BM, B_ * H_);                  // (32, 32, 32)
  scores_kernel<<<gsc, blk, 0, stream>>>(qh, kh, mask, attn);

  softmax_kernel<<<B_ * H_ * S_, 256, 0, stream>>>(attn);

  dim3 gpv(1, S_ / BM, B_ * H_);                        // (1, 32, 32)
  pv_kernel<<<gpv, blk, 0, stream>>>(attn, vh, ctx);

  out_proj_kernel<<<gproj, blk, 0, stream>>>(ctx, wo, bo, out);
}

// Round 2
// 1421.151 us; speedup vs baseline: 1.3839x; 1.3839x over previous
//
#include <hip/hip_runtime.h>
#include <math.h>

// Problem constants (B=2, S=2048, D=1024, H=16, DEPTH=64)
#define B_ 2
#define S_ 2048
#define D_ 1024
#define H_ 16
#define DH_ 64

// LDS tile row stride in bf16 elements (64 data + 16 pad -> 160B rows,
// 16B-aligned for ds_read_b128, 4-way max bank aliasing instead of 16-way)
#define LDW 80

typedef __attribute__((ext_vector_type(8))) short short8;   // 8 bf16 = 4 VGPRs
typedef __attribute__((ext_vector_type(4))) float floatx4;  // MFMA C/D

__device__ __forceinline__ unsigned short f2bf(float f) {
  union { float f; unsigned u; } x; x.f = f;
  unsigned r = x.u + 0x7fffu + ((x.u >> 16) & 1u);  // RNE
  return (unsigned short)(r >> 16);
}

// ---------------------------------------------------------------------------
// Staging: R rows x 64 cols into LDS (stride LDW), converting fp32 -> bf16.
// 256 threads. lda = source row stride (elements).
// ---------------------------------------------------------------------------
template <int R>
__device__ __forceinline__ void stage_f32_64(const float* __restrict__ src, int lda,
                                             unsigned short* __restrict__ lds) {
#pragma unroll
  for (int t = 0; t < R / 16; ++t) {
    const int c = t * 256 + threadIdx.x;   // float4 chunk index
    const int row = c >> 4;
    const int col = (c & 15) << 2;
    const float4 v = *(const float4*)(src + (size_t)row * lda + col);
    ushort4 u;
    u.x = f2bf(v.x); u.y = f2bf(v.y); u.z = f2bf(v.z); u.w = f2bf(v.w);
    *(ushort4*)(lds + row * LDW + col) = u;
  }
}

// Staging: R rows x 64 cols of bf16 into LDS (stride LDW). 256 threads.
template <int R>
__device__ __forceinline__ void stage_bf16_64(const unsigned short* __restrict__ src, int lda,
                                              unsigned short* __restrict__ lds) {
#pragma unroll
  for (int t = 0; t < R / 32; ++t) {
    const int c = t * 256 + threadIdx.x;   // 8-element chunk index
    const int row = c >> 3;
    const int col = (c & 7) << 3;
    const uint4 v = *(const uint4*)(src + (size_t)row * lda + col);
    *(uint4*)(lds + row * LDW + col) = v;
  }
}

// ---------------------------------------------------------------------------
// One wave computes a 64x64 C-tile as 4x4 MFMAs of 16x16x32 over a staged
// K=64 chunk. lA/lB pre-offset to the wave's 64-row span.
// A-frag: A[m=lane&15][k=(lane>>4)*8+j]; B-frag: B[n=lane&15][k=...] (NT).
// C/D: col=lane&15, row=(lane>>4)*4+reg  [m89/m91 verified].
// ---------------------------------------------------------------------------
__device__ __forceinline__ void wave_mfma_64x64(const unsigned short* __restrict__ lA,
                                                const unsigned short* __restrict__ lB,
                                                floatx4 acc[4][4]) {
  const int lane = threadIdx.x & 63;
  const int lr = lane & 15, lq = lane >> 4;
#pragma unroll
  for (int ks = 0; ks < 2; ++ks) {
    short8 a[4], b[4];
#pragma unroll
    for (int i = 0; i < 4; ++i)
      a[i] = *reinterpret_cast<const short8*>(lA + (i * 16 + lr) * LDW + lq * 8 + ks * 32);
#pragma unroll
    for (int j = 0; j < 4; ++j)
      b[j] = *reinterpret_cast<const short8*>(lB + (j * 16 + lr) * LDW + lq * 8 + ks * 32);
#pragma unroll
    for (int i = 0; i < 4; ++i)
#pragma unroll
      for (int j = 0; j < 4; ++j)
        acc[i][j] = __builtin_amdgcn_mfma_f32_16x16x32_bf16(a[i], b[j], acc[i][j], 0, 0, 0);
  }
}

// ---------------------------------------------------------------------------
// Projection GEMM: C[4096x1024] = A[4096x1024] @ W[1024x1024]^T + bias.
// 128x128 tile, 4 waves (2x2), K staged in chunks of 64.
// OUT_MODE: 0 = bf16 head-split [B,H,S,DH]; 1 = bf16 head-split-T [B,H,DH,S];
//           2 = fp32 flat [4096x1024].
// ---------------------------------------------------------------------------
template <bool A_BF16, int OUT_MODE>
__global__ __launch_bounds__(256) void gemm_nt_1024(
    const void* __restrict__ Ap, const float* __restrict__ W,
    const float* __restrict__ bias, void* __restrict__ outp) {
  __shared__ unsigned short lA[128 * LDW];
  __shared__ unsigned short lB[128 * LDW];
  const int m0 = blockIdx.y * 128, n0 = blockIdx.x * 128;
  const int wave = threadIdx.x >> 6;
  const int wm = wave >> 1, wn = wave & 1;
  floatx4 acc[4][4];
#pragma unroll
  for (int i = 0; i < 4; ++i)
#pragma unroll
    for (int j = 0; j < 4; ++j) acc[i][j] = (floatx4){0.f, 0.f, 0.f, 0.f};

  for (int k0 = 0; k0 < 1024; k0 += 64) {
    __syncthreads();
    if (A_BF16)
      stage_bf16_64<128>((const unsigned short*)Ap + (size_t)m0 * 1024 + k0, 1024, lA);
    else
      stage_f32_64<128>((const float*)Ap + (size_t)m0 * 1024 + k0, 1024, lA);
    stage_f32_64<128>(W + (size_t)n0 * 1024 + k0, 1024, lB);
    __syncthreads();
    wave_mfma_64x64(lA + wm * 64 * LDW, lB + wn * 64 * LDW, acc);
  }

  const int lane = threadIdx.x & 63;
  const int lr = lane & 15, lq = lane >> 4;
#pragma unroll
  for (int j = 0; j < 4; ++j) {
    const int gn = n0 + wn * 64 + j * 16 + lr;
    const float bs = bias[gn];
#pragma unroll
    for (int i = 0; i < 4; ++i) {
#pragma unroll
      for (int r = 0; r < 4; ++r) {
        const int gm = m0 + wm * 64 + i * 16 + lq * 4 + r;
        const float val = acc[i][j][r] + bs;
        if (OUT_MODE == 0) {
          const int b = gm >> 11, s = gm & (S_ - 1);
          const int h = gn >> 6, dd = gn & (DH_ - 1);
          ((unsigned short*)outp)[(((size_t)(b * H_ + h) * S_ + s) << 6) + dd] = f2bf(val);
        } else if (OUT_MODE == 1) {
          const int b = gm >> 11, s = gm & (S_ - 1);
          const int h = gn >> 6, dd = gn & (DH_ - 1);
          ((unsigned short*)outp)[(((size_t)(b * H_ + h) * DH_ + dd) << 11) + s] = f2bf(val);
        } else {
          ((float*)outp)[(size_t)gm * D_ + gn] = val;
        }
      }
    }
  }
}

// ---------------------------------------------------------------------------
// Scores: logits = (qh @ kh^T)/8 + mask*-1e9 per (b,h). M=N=2048, K=64.
// fp32 output straight into the attn region of d_out.
// ---------------------------------------------------------------------------
__global__ __launch_bounds__(256) void scores_mfma(
    const unsigned short* __restrict__ qh, const unsigned short* __restrict__ kh,
    const float* __restrict__ mask, float* __restrict__ attn) {
  __shared__ unsigned short lA[128 * LDW];
  __shared__ unsigned short lB[128 * LDW];
  const int z = blockIdx.z;
  const int m0 = blockIdx.y * 128, n0 = blockIdx.x * 128;
  const int wave = threadIdx.x >> 6;
  const int wm = wave >> 1, wn = wave & 1;
  floatx4 acc[4][4];
#pragma unroll
  for (int i = 0; i < 4; ++i)
#pragma unroll
    for (int j = 0; j < 4; ++j) acc[i][j] = (floatx4){0.f, 0.f, 0.f, 0.f};

  stage_bf16_64<128>(qh + (size_t)z * S_ * DH_ + (size_t)m0 * DH_, DH_, lA);
  stage_bf16_64<128>(kh + (size_t)z * S_ * DH_ + (size_t)n0 * DH_, DH_, lB);
  __syncthreads();
  wave_mfma_64x64(lA + wm * 64 * LDW, lB + wn * 64 * LDW, acc);

  const int lane = threadIdx.x & 63;
  const int lr = lane & 15, lq = lane >> 4;
  float* out = attn + (size_t)z * S_ * S_;
  const float* mrow = mask + (size_t)(z >> 4) * S_;
#pragma unroll
  for (int j = 0; j < 4; ++j) {
    const int gn = n0 + wn * 64 + j * 16 + lr;
    const float mk = mrow[gn] * (-1e9f);
#pragma unroll
    for (int i = 0; i < 4; ++i) {
#pragma unroll
      for (int r = 0; r < 4; ++r) {
        const int gm = m0 + wm * 64 + i * 16 + lq * 4 + r;
        out[(size_t)gm * S_ + gn] = acc[i][j][r] * 0.125f + mk;
      }
    }
  }
}

// ---------------------------------------------------------------------------
// In-place row softmax over attn rows of length S_ (one block per row)
// ---------------------------------------------------------------------------
__global__ __launch_bounds__(256) void softmax_kernel(float* __restrict__ attn) {
  __shared__ float red[8];
  const int row = blockIdx.x;
  float* p = attn + (size_t)row * S_;
  const int tid = threadIdx.x;
  float v[8];
  float mx = -3.4e38f;
#pragma unroll
  for (int i = 0; i < 8; ++i) {
    v[i] = p[tid + 256 * i];
    mx = fmaxf(mx, v[i]);
  }
#pragma unroll
  for (int off = 32; off > 0; off >>= 1) mx = fmaxf(mx, __shfl_down(mx, off, 64));
  if ((tid & 63) == 0) red[tid >> 6] = mx;
  __syncthreads();
  mx = fmaxf(fmaxf(red[0], red[1]), fmaxf(red[2], red[3]));
  float s = 0.f;
#pragma unroll
  for (int i = 0; i < 8; ++i) {
    v[i] = __expf(v[i] - mx);
    s += v[i];
  }
#pragma unroll
  for (int off = 32; off > 0; off >>= 1) s += __shfl_down(s, off, 64);
  if ((tid & 63) == 0) red[4 + (tid >> 6)] = s;
  __syncthreads();
  s = red[4] + red[5] + red[6] + red[7];
  const float inv = 1.f / s;
#pragma unroll
  for (int i = 0; i < 8; ++i) p[tid + 256 * i] = v[i] * inv;
}

// ---------------------------------------------------------------------------
// PV: ctx[b,s, h*64+dd] = sum_k attn[z][s][k] * vhT[z][dd][k].
// Tile 256x64, 4 waves stacked in M. attn converted fp32->bf16 in staging.
// ---------------------------------------------------------------------------
__global__ __launch_bounds__(256) void pv_mfma(
    const float* __restrict__ attn, const unsigned short* __restrict__ vhT,
    unsigned short* __restrict__ ctx) {
  __shared__ unsigned short lA[256 * LDW];  // 40 KB
  __shared__ unsigned short lB[64 * LDW];   // 10 KB
  const int z = blockIdx.z;
  const int m0 = blockIdx.y * 256;
  const int wm = threadIdx.x >> 6;
  const float* A = attn + (size_t)z * S_ * S_ + (size_t)m0 * S_;
  const unsigned short* Bv = vhT + (size_t)z * DH_ * S_;
  floatx4 acc[4][4];
#pragma unroll
  for (int i = 0; i < 4; ++i)
#pragma unroll
    for (int j = 0; j < 4; ++j) acc[i][j] = (floatx4){0.f, 0.f, 0.f, 0.f};

  for (int k0 = 0; k0 < S_; k0 += 64) {
    __syncthreads();
    stage_f32_64<256>(A + k0, S_, lA);
    stage_bf16_64<64>(Bv + k0, S_, lB);
    __syncthreads();
    wave_mfma_64x64(lA + wm * 64 * LDW, lB, acc);
  }

  const int lane = threadIdx.x & 63;
  const int lr = lane & 15, lq = lane >> 4;
  const int b = z >> 4, h = z & (H_ - 1);
#pragma unroll
  for (int i = 0; i < 4; ++i) {
#pragma unroll
    for (int r = 0; r < 4; ++r) {
      const int s = m0 + wm * 64 + i * 16 + lq * 4 + r;
#pragma unroll
      for (int j = 0; j < 4; ++j) {
        const int dd = j * 16 + lr;
        ctx[((size_t)(b * S_ + s) << 10) + h * DH_ + dd] = f2bf(acc[i][j][r]);
      }
    }
  }
}

// ---------------------------------------------------------------------------
extern "C" void kernel_launch(void* const* d_in, const int* in_sizes, int n_in,
                              void* d_out, int out_size, void* d_ws, size_t ws_size,
                              hipStream_t stream) {
  const float* q    = (const float*)d_in[0];
  const float* k    = (const float*)d_in[1];
  const float* v    = (const float*)d_in[2];
  const float* mask = (const float*)d_in[3];
  const float* wq   = (const float*)d_in[4];
  const float* bq   = (const float*)d_in[5];
  const float* wk   = (const float*)d_in[6];
  const float* bk   = (const float*)d_in[7];
  const float* wv   = (const float*)d_in[8];
  const float* bv   = (const float*)d_in[9];
  const float* wo   = (const float*)d_in[10];
  const float* bo   = (const float*)d_in[11];

  float* out  = (float*)d_out;               // [B,S,D] fp32
  float* attn = out + (size_t)B_ * S_ * D_;  // [B,H,S,S] fp32

  // workspace (bf16): qh, kh [B,H,S,DH]; vhT [B,H,DH,S]; ctx [B,S,D] = 33.6 MB
  unsigned short* qh_bf  = (unsigned short*)d_ws;
  unsigned short* kh_bf  = qh_bf + (size_t)B_ * S_ * D_;
  unsigned short* vhT_bf = kh_bf + (size_t)B_ * S_ * D_;
  unsigned short* ctx_bf = vhT_bf + (size_t)B_ * S_ * D_;

  dim3 gproj(D_ / 128, (B_ * S_) / 128);     // (8, 32)
  gemm_nt_1024<false, 0><<<gproj, 256, 0, stream>>>(q, wq, bq, qh_bf);
  gemm_nt_1024<false, 0><<<gproj, 256, 0, stream>>>(k, wk, bk, kh_bf);
  gemm_nt_1024<false, 1><<<gproj, 256, 0, stream>>>(v, wv, bv, vhT_bf);

  dim3 gsc(S_ / 128, S_ / 128, B_ * H_);     // (16, 16, 32)
  scores_mfma<<<gsc, 256, 0, stream>>>(qh_bf, kh_bf, mask, attn);

  softmax_kernel<<<B_ * H_ * S_, 256, 0, stream>>>(attn);

  dim3 gpv(1, S_ / 256, B_ * H_);            // (1, 8, 32)
  pv_mfma<<<gpv, 256, 0, stream>>>(attn, vhT_bf, ctx_bf);

  gemm_nt_1024<true, 2><<<gproj, 256, 0, stream>>>(ctx_bf, wo, bo, out);
}